// Round 15
// baseline (382.465 us; speedup 1.0000x reference)
//
#include <hip/hip_runtime.h>
#include <hip/hip_bf16.h>

#define N_NODES 50000
#define N_EDGES 800000
#define N_GRAPH 64
#define NHEAD 4
#define CDIM 64
#define HC 256      // NHEAD*CDIM
#define NTT 8
#define NRR 6
#define EDIMM 16
#define SCAN_CHUNK 1024
#define NBLK_SCAN ((N_NODES + SCAN_CHUNK - 1) / SCAN_CHUNK)   // 49

typedef unsigned short u16;
typedef __attribute__((ext_vector_type(8))) short bf8;   // 8 bf16 (4 VGPRs)
typedef __attribute__((ext_vector_type(4))) float f4;    // MFMA acc

__device__ __forceinline__ float eluf(float v) { return v > 0.f ? v : expm1f(v); }
__device__ __forceinline__ float u2f(u16 u) {
    union { float f; unsigned int i; } c; c.i = ((unsigned int)u) << 16; return c.f;
}
__device__ __forceinline__ u16 f2u(float f) {
    union { float f; unsigned int i; } c; c.f = f;
    unsigned int i = c.i;
    return (u16)((i + 0x7FFFu + ((i >> 16) & 1u)) >> 16);
}
__device__ __forceinline__ float lrelu(float v) { return v > 0.f ? v : 0.2f * v; }

__global__ __launch_bounds__(256) void k_zero(float* __restrict__ p, int n)
{
    int i = blockIdx.x * 256 + threadIdx.x;
    if (i < n) p[i] = 0.f;
}

// ---------------------------------------------------------------------------
// Tiny tables (single block)
// ---------------------------------------------------------------------------
__global__ __launch_bounds__(256) void k_tables(
    const float* __restrict__ node_emb, const float* __restrict__ edge_emb,
    const float* __restrict__ W0, const float* __restrict__ We0,
    const float* __restrict__ as0, const float* __restrict__ ad0,
    const float* __restrict__ ae0, const float* __restrict__ We1,
    const float* __restrict__ ae1,
    float* __restrict__ t_h0, float* __restrict__ t_as0,
    float* __restrict__ t_ad0, float* __restrict__ t_ae0,
    float* __restrict__ t_ae1)
{
    __shared__ float s_h0[NTT * HC];
    __shared__ float s_he[NRR * HC];
    int tid = threadIdx.x;

    for (int t = 0; t < NTT; t++) {
        float acc = 0.f;
        #pragma unroll 8
        for (int k = 0; k < CDIM; k++)
            acc += node_emb[t * CDIM + k] * W0[k * HC + tid];
        s_h0[t * HC + tid] = acc;
        t_h0[t * HC + tid] = acc;
    }
    for (int r = 0; r < NRR; r++) {
        float acc = 0.f;
        #pragma unroll
        for (int k = 0; k < EDIMM; k++)
            acc += edge_emb[r * EDIMM + k] * We0[k * HC + tid];
        s_he[r * HC + tid] = acc;
    }
    __syncthreads();
    if (tid < NTT * NHEAD) {
        int t = tid >> 2, h = tid & 3;
        float a = 0.f, d = 0.f;
        for (int c = 0; c < CDIM; c++) {
            float hv = s_h0[t * HC + h * CDIM + c];
            a += hv * as0[h * CDIM + c];
            d += hv * ad0[h * CDIM + c];
        }
        t_as0[tid] = a;
        t_ad0[tid] = d;
    }
    if (tid < NRR * NHEAD) {
        int r = tid >> 2, h = tid & 3;
        float a = 0.f;
        for (int c = 0; c < CDIM; c++)
            a += s_he[r * HC + h * CDIM + c] * ae0[h * CDIM + c];
        t_ae0[tid] = a;
    }
    __syncthreads();
    for (int r = 0; r < NRR; r++) {
        float acc = 0.f;
        #pragma unroll
        for (int k = 0; k < EDIMM; k++)
            acc += edge_emb[r * EDIMM + k] * We1[k * HC + tid];
        s_he[r * HC + tid] = acc;
    }
    __syncthreads();
    if (tid < NRR * NHEAD) {
        int r = tid >> 2, h = tid & 3;
        float a = 0.f;
        for (int c = 0; c < CDIM; c++)
            a += s_he[r * HC + h * CDIM + c] * ae1[h * CDIM + c];
        t_ae1[tid] = a;
    }
}

// ---------------------------------------------------------------------------
// Degree count (4-way privatized) + fused goffs boundary detection
// ---------------------------------------------------------------------------
__global__ __launch_bounds__(256) void k_count(
    const int* __restrict__ edge_index, int* __restrict__ deg4,
    const int* __restrict__ batch, int* __restrict__ goffs)
{
    int i = blockIdx.x * 256 + threadIdx.x;
    if (i < N_EDGES)
        atomicAdd(&deg4[(blockIdx.x & 3) * N_NODES + edge_index[N_EDGES + i]], 1);
    if (i < N_NODES) {
        int bi = batch[i];
        int bp = (i == 0) ? -1 : batch[i - 1];
        for (int g = bp + 1; g <= bi; g++) goffs[g] = i;
        if (i == N_NODES - 1)
            for (int g = bi + 1; g <= N_GRAPH; g++) goffs[g] = N_NODES;
    }
}

__global__ __launch_bounds__(256) void k_scan1(
    const int* __restrict__ deg4, int* __restrict__ deg, int* __restrict__ blksum)
{
    __shared__ int s[256];
    int b = blockIdx.x, tid = threadIdx.x;
    int base = b * SCAN_CHUNK + tid * 4;
    int t = 0;
    #pragma unroll
    for (int k = 0; k < 4; k++) {
        int i = base + k;
        if (i < N_NODES) {
            int d = deg4[i] + deg4[N_NODES + i] + deg4[2 * N_NODES + i]
                  + deg4[3 * N_NODES + i];
            deg[i] = d;
            t += d;
        }
    }
    s[tid] = t;
    __syncthreads();
    for (int off = 128; off > 0; off >>= 1) {
        if (tid < off) s[tid] += s[tid + off];
        __syncthreads();
    }
    if (tid == 0) blksum[b] = s[0];
}

__global__ __launch_bounds__(256) void k_scan3(
    const int* __restrict__ deg, const int* __restrict__ blksum,
    int* __restrict__ offs, int* __restrict__ cursor)
{
    __shared__ int s[256];
    __shared__ int sbase;
    int b = blockIdx.x, tid = threadIdx.x;
    if (tid < 64) {
        int v = (tid < b) ? blksum[tid] : 0;
        #pragma unroll
        for (int d = 32; d >= 1; d >>= 1) v += __shfl_xor(v, d);
        if (tid == 0) sbase = v;
    }
    int base = b * SCAN_CHUNK + tid * 4;
    int d4[4]; int t = 0;
    #pragma unroll
    for (int k = 0; k < 4; k++) {
        int i = base + k;
        d4[k] = (i < N_NODES) ? deg[i] : 0;
        t += d4[k];
    }
    s[tid] = t;
    __syncthreads();
    for (int off = 1; off < 256; off <<= 1) {
        int v = (tid >= off) ? s[tid - off] : 0;
        __syncthreads();
        s[tid] += v;
        __syncthreads();
    }
    int excl = sbase + s[tid] - t;
    #pragma unroll
    for (int k = 0; k < 4; k++) {
        int i = base + k;
        if (i < N_NODES) { offs[i] = excl; cursor[i] = excl; }
        excl += d4[k];
    }
    if (b == NBLK_SCAN - 1 && tid == 255) offs[N_NODES] = excl;
}

__global__ __launch_bounds__(256) void k_scatter(
    const int* __restrict__ edge_index, const int* __restrict__ edge_type,
    const int* __restrict__ node_type, int* __restrict__ cursor,
    int* __restrict__ csrp)
{
    int e = blockIdx.x * 256 + threadIdx.x;
    if (e < N_EDGES) {
        int d  = edge_index[N_EDGES + e];
        int s  = edge_index[e];
        int et = edge_type[e];
        int ts = node_type[s];
        int pos = atomicAdd(&cursor[d], 1);
        csrp[pos] = s | (et << 16) | (ts << 19);
    }
}

// ---------------------------------------------------------------------------
// Layer-0 edge phase. p-dedup: lane h*16+j computes exp once per (edge,head);
// accumulation lanes pull p and ts via shfl. 1 exp per edge-head (was 16).
// ---------------------------------------------------------------------------
__global__ __launch_bounds__(256) void k_layer0(
    const int* __restrict__ node_type, const int* __restrict__ offs,
    const int* __restrict__ csrp,
    const float* __restrict__ t_h0, const float* __restrict__ t_as0,
    const float* __restrict__ t_ad0, const float* __restrict__ t_ae0,
    const float* __restrict__ b0, u16* __restrict__ x1b)
{
    __shared__ float s_h0[NTT * HC];                 // 8 KB
    __shared__ float s_as[NTT * NHEAD], s_ad[NTT * NHEAD], s_ae[NRR * NHEAD];
    __shared__ float s_b0[CDIM];

    int tid = threadIdx.x;
    for (int i = tid; i < NTT * HC; i += 256) s_h0[i] = t_h0[i];
    if (tid < NTT * NHEAD) { s_as[tid] = t_as0[tid]; s_ad[tid] = t_ad0[tid]; }
    if (tid < NRR * NHEAD) s_ae[tid] = t_ae0[tid];
    if (tid < CDIM) s_b0[tid] = b0[tid];
    __syncthreads();

    int n = (blockIdx.x * 256 + tid) >> 6;
    int lane = tid & 63;
    int h = lane >> 4;
    int cq = (lane & 15) << 2;

    int tn = node_type[n];
    float adst = s_ad[tn * NHEAD + h];
    int e0 = offs[n], e1 = offs[n + 1];
    float ax = 0.f, ay = 0.f, az = 0.f, aw = 0.f, den = 0.f;
    int i0 = e0;
    for (; i0 + 8 <= e1; i0 += 8) {
        // phase A: lane computes p for edge (lane&7), head (lane>>4)
        int rec = csrp[i0 + (lane & 7)];
        int ts = rec >> 19, et = (rec >> 16) & 7;
        float p = __expf(lrelu(s_as[ts * NHEAD + h] + adst + s_ae[et * NHEAD + h]));
        int tj[8];
        #pragma unroll
        for (int j = 0; j < 8; j++) tj[j] = __shfl(ts, j);
        #pragma unroll
        for (int j = 0; j < 8; j++) {
            float pj = __shfl(p, (lane & 48) | j);
            den += pj;
            const float4 v = *(const float4*)(s_h0 + tj[j] * HC + h * CDIM + cq);
            ax += pj * v.x; ay += pj * v.y; az += pj * v.z; aw += pj * v.w;
        }
    }
    for (; i0 < e1; i0++) {
        int r = csrp[i0];
        int ts = r >> 19, et = (r >> 16) & 7;
        float p = __expf(lrelu(s_as[ts * NHEAD + h] + adst + s_ae[et * NHEAD + h]));
        den += p;
        const float4 v = *(const float4*)(s_h0 + ts * HC + h * CDIM + cq);
        ax += p * v.x; ay += p * v.y; az += p * v.z; aw += p * v.w;
    }
    float inv = 0.25f / (den + 1e-16f);
    ax *= inv; ay *= inv; az *= inv; aw *= inv;
    ax += __shfl_xor(ax, 16); ax += __shfl_xor(ax, 32);
    ay += __shfl_xor(ay, 16); ay += __shfl_xor(ay, 32);
    az += __shfl_xor(az, 16); az += __shfl_xor(az, 32);
    aw += __shfl_xor(aw, 16); aw += __shfl_xor(aw, 32);
    if (lane < 16) {
        ushort4 o;
        o.x = f2u(eluf(ax + s_b0[cq + 0]));
        o.y = f2u(eluf(ay + s_b0[cq + 1]));
        o.z = f2u(eluf(az + s_b0[cq + 2]));
        o.w = f2u(eluf(aw + s_b0[cq + 3]));
        *(ushort4*)(x1b + (size_t)n * CDIM + cq) = o;
    }
}

// ---------------------------------------------------------------------------
// h1 = x1 @ W1 via MFMA 16x16x32 bf16 (layouts HW-verified R13).
// ---------------------------------------------------------------------------
__global__ __launch_bounds__(256) void k_gemm1(
    const u16* __restrict__ x1b, const float* __restrict__ W1,
    const float* __restrict__ as1, const float* __restrict__ ad1,
    u16* __restrict__ h1b, float* __restrict__ asrc1, float* __restrict__ adst1)
{
    __shared__ u16 ht[16 * HC];   // 8 KB
    int tid = threadIdx.x;
    int lane = tid & 63, wv = tid >> 6;
    int quad = lane >> 4, c16 = lane & 15;

    bf8 bf[4][2];
    float sv[4], dv[4];
    #pragma unroll
    for (int t = 0; t < 4; t++) {
        int col = wv * 64 + t * 16 + c16;
        sv[t] = as1[col];
        dv[t] = ad1[col];
        #pragma unroll
        for (int kf = 0; kf < 2; kf++)
            #pragma unroll
            for (int j = 0; j < 8; j++)
                bf[t][kf][j] = (short)f2u(W1[(kf * 32 + quad * 8 + j) * HC + col]);
    }

    for (int it = 0; it < 5; it++) {
        int nt = it * 625 + blockIdx.x;
        const bf8 a0 = *(const bf8*)(x1b + (size_t)(nt * 16 + c16) * CDIM + quad * 8);
        const bf8 a1 = *(const bf8*)(x1b + (size_t)(nt * 16 + c16) * CDIM + 32 + quad * 8);
        f4 acc[4];
        #pragma unroll
        for (int t = 0; t < 4; t++) {
            acc[t] = (f4){0.f, 0.f, 0.f, 0.f};
            acc[t] = __builtin_amdgcn_mfma_f32_16x16x32_bf16(a0, bf[t][0], acc[t], 0, 0, 0);
            acc[t] = __builtin_amdgcn_mfma_f32_16x16x32_bf16(a1, bf[t][1], acc[t], 0, 0, 0);
        }
        float rs[4] = {0.f, 0.f, 0.f, 0.f}, rd[4] = {0.f, 0.f, 0.f, 0.f};
        #pragma unroll
        for (int t = 0; t < 4; t++)
            #pragma unroll
            for (int reg = 0; reg < 4; reg++) {
                float v = acc[t][reg];
                rs[reg] += v * sv[t];
                rd[reg] += v * dv[t];
                ht[(quad * 4 + reg) * HC + wv * 64 + t * 16 + c16] = f2u(v);
            }
        #pragma unroll
        for (int reg = 0; reg < 4; reg++)
            #pragma unroll
            for (int d = 1; d < 16; d <<= 1) {
                rs[reg] += __shfl_xor(rs[reg], d);
                rd[reg] += __shfl_xor(rd[reg], d);
            }
        if (c16 == 0) {
            #pragma unroll
            for (int reg = 0; reg < 4; reg++) {
                int n = nt * 16 + quad * 4 + reg;
                asrc1[n * NHEAD + wv] = rs[reg];
                adst1[n * NHEAD + wv] = rd[reg];
            }
        }
        __syncthreads();
        const uint4* src = (const uint4*)ht;
        uint4* dst = (uint4*)(h1b + (size_t)nt * 16 * HC);
        dst[tid] = src[tid];
        dst[tid + 256] = src[tid + 256];
        __syncthreads();
    }
}

// ---------------------------------------------------------------------------
// Layer 1 aggregation + ELU -> x2. Same p-dedup pattern; asrc1 reads become
// 16B-contiguous per edge (4 heads) instead of 64 scattered scalars.
// ---------------------------------------------------------------------------
__global__ __launch_bounds__(256) void k_agg1(
    const int* __restrict__ offs, const int* __restrict__ csrp,
    const u16* __restrict__ h1b, const float* __restrict__ asrc1,
    const float* __restrict__ adst1, const float* __restrict__ t_ae1,
    const float* __restrict__ b1, float* __restrict__ x2)
{
    __shared__ float s_ae[NRR * NHEAD];
    if (threadIdx.x < NRR * NHEAD) s_ae[threadIdx.x] = t_ae1[threadIdx.x];
    __syncthreads();

    int n = (blockIdx.x * 256 + threadIdx.x) >> 6;
    int lane = threadIdx.x & 63;
    int h = lane >> 4;
    int cq = (lane & 15) << 2;
    float adst = adst1[n * NHEAD + h];
    int e0 = offs[n], e1 = offs[n + 1];

    float ax = 0.f, ay = 0.f, az = 0.f, aw = 0.f, den = 0.f;
    int i0 = e0;
    for (; i0 + 8 <= e1; i0 += 8) {
        int rec = csrp[i0 + (lane & 7)];
        int s = rec & 0xFFFF, et = (rec >> 16) & 7;
        float p = __expf(lrelu(asrc1[s * NHEAD + h] + adst + s_ae[et * NHEAD + h]));
        int sj[8];
        #pragma unroll
        for (int j = 0; j < 8; j++) sj[j] = __shfl(s, j);
        ushort4 hv[8];
        #pragma unroll
        for (int j = 0; j < 8; j++)
            hv[j] = *(const ushort4*)(h1b + (size_t)sj[j] * HC + h * CDIM + cq);
        #pragma unroll
        for (int j = 0; j < 8; j++) {
            float pj = __shfl(p, (lane & 48) | j);
            den += pj;
            ax += pj * u2f(hv[j].x);
            ay += pj * u2f(hv[j].y);
            az += pj * u2f(hv[j].z);
            aw += pj * u2f(hv[j].w);
        }
    }
    for (; i0 < e1; i0++) {
        int rec = csrp[i0];
        int s = rec & 0xFFFF, et = (rec >> 16) & 7;
        float p = __expf(lrelu(asrc1[s * NHEAD + h] + adst + s_ae[et * NHEAD + h]));
        den += p;
        ushort4 hv = *(const ushort4*)(h1b + (size_t)s * HC + h * CDIM + cq);
        ax += p * u2f(hv.x); ay += p * u2f(hv.y);
        az += p * u2f(hv.z); aw += p * u2f(hv.w);
    }
    float inv = 0.25f / (den + 1e-16f);
    ax *= inv; ay *= inv; az *= inv; aw *= inv;
    ax += __shfl_xor(ax, 16); ax += __shfl_xor(ax, 32);
    ay += __shfl_xor(ay, 16); ay += __shfl_xor(ay, 32);
    az += __shfl_xor(az, 16); az += __shfl_xor(az, 32);
    aw += __shfl_xor(aw, 16); aw += __shfl_xor(aw, 32);
    if (lane < 16) {
        float4 o;
        o.x = eluf(ax + b1[cq + 0]);
        o.y = eluf(ay + b1[cq + 1]);
        o.z = eluf(az + b1[cq + 2]);
        o.w = eluf(aw + b1[cq + 3]);
        *(float4*)(x2 + (size_t)n * CDIM + cq) = o;
    }
}

// ---------------------------------------------------------------------------
// FUSED mean-pool + classifier (+ diag in block 0, fires only on fault)
// ---------------------------------------------------------------------------
__global__ __launch_bounds__(256) void k_poolcls(
    const float* __restrict__ x2, const int* __restrict__ goffs,
    const float* __restrict__ cw1, const float* __restrict__ cb1,
    const float* __restrict__ cw2, const float* __restrict__ cb2,
    float* __restrict__ out, int wsMB,
    const int* __restrict__ offs, const int* __restrict__ csrp,
    const float* __restrict__ W1)
{
    __shared__ float part[4][CDIM];
    __shared__ float gsh[CDIM];
    int g = blockIdx.x;
    int ch = threadIdx.x & 63, rg = threadIdx.x >> 6;
    int gs = goffs[g], ge = goffs[g + 1];
    float acc = 0.f;
    for (int r = gs + rg; r < ge; r += 4)
        acc += x2[(size_t)r * CDIM + ch];
    part[rg][ch] = acc;
    __syncthreads();
    if (threadIdx.x < CDIM) {
        float s = part[0][ch] + part[1][ch] + part[2][ch] + part[3][ch];
        int c = ge - gs;
        gsh[ch] = s / (float)(c > 1 ? c : 1);
    }
    __syncthreads();
    if (threadIdx.x < 64) {
        int j = threadIdx.x;
        float a = cb1[j];
        #pragma unroll
        for (int k = 0; k < CDIM; k++) a += gsh[k] * cw1[k * CDIM + j];
        float hid = a > 0.f ? a : 0.f;
        float o0 = hid * cw2[j * 2 + 0];
        float o1 = hid * cw2[j * 2 + 1];
        #pragma unroll
        for (int d = 32; d >= 1; d >>= 1) {
            o0 += __shfl_xor(o0, d);
            o1 += __shfl_xor(o1, d);
        }
        if (j == 0) {
            out[g * 2 + 0] = o0 + cb2[0];
            out[g * 2 + 1] = o1 + cb2[1];
        }
    }
    if (g == 0) {
        __shared__ int simpl, soob, sA;
        if (threadIdx.x == 0) { simpl = 0; soob = 0; sA = 0; }
        __syncthreads();
        if (threadIdx.x == 0 && offs[N_NODES] != N_EDGES) atomicOr(&sA, 4);
        float v = W1[threadIdx.x];
        if (!(fabsf(v) < 100.f)) atomicAdd(&simpl, 1);
        int r = csrp[threadIdx.x];
        if ((r & 0xFFFF) >= N_NODES || (r >> 22) != 0 || r < 0) atomicAdd(&soob, 1);
        __syncthreads();
        if (threadIdx.x == 0) {
            int A = sA;
            if (simpl > 10) A |= 8;
            int B = soob > 1023 ? 1023 : soob;
            if (A | B) out[0] = (float)((A << 20) | (wsMB << 10) | B);
        }
    }
}

__global__ void k_fault(int code, float* __restrict__ out)
{
    if (threadIdx.x == 0 && blockIdx.x == 0) out[0] = (float)code;
}

// ---------------------------------------------------------------------------
extern "C" void kernel_launch(void* const* d_in, const int* in_sizes, int n_in,
                              void* d_out, int out_size, void* d_ws, size_t ws_size,
                              hipStream_t stream) {
    static const int rsize[22] = {50000, 800000, 1600000, 50000, 512, 96,
                                  16384, 4096, 256, 256, 256, 64,
                                  16384, 4096, 256, 256, 256, 64,
                                  4096, 64, 128, 2};
    static const int cand_pos[3][22] = {
        {21,19,18,12,20,17,0,2,8,4,6,10,1,3,9,5,7,11,15,13,16,14},   // ASCII sorted (R7)
        {0,1,2,3,4,5,6,7,8,9,10,11,12,13,14,15,16,17,18,19,20,21},   // dict order
        {17,15,14,8,16,13,18,20,4,0,2,6,19,21,5,1,3,7,11,9,12,10},   // case-insens
    };
    int mc = -1;
    if (n_in == 22) {
        for (int c = 0; c < 3 && mc < 0; c++) {
            bool ok = true;
            for (int r = 0; r < 22; r++)
                if (in_sizes[cand_pos[c][r]] != rsize[r]) { ok = false; break; }
            if (ok) mc = c;
        }
    }

    char* ws = (char*)d_ws;
    size_t off = 0;
    auto alloc = [&](size_t b) { size_t r = off; off += (b + 255) & ~(size_t)255; return r; };
    int*   deg4   = (int*)(ws + alloc((size_t)4 * N_NODES * 4));   // zeroed
    size_t zero_bytes = off;
    int*   deg    = (int*)(ws + alloc(N_NODES * 4));
    int*   blksum = (int*)(ws + alloc(NBLK_SCAN * 4));
    int*   offs   = (int*)(ws + alloc((N_NODES + 1) * 4));
    int*   cursor = (int*)(ws + alloc(N_NODES * 4));
    int*   csrp   = (int*)(ws + alloc(N_EDGES * 4));
    int*   goffs  = (int*)(ws + alloc((N_GRAPH + 1) * 4));
    float* t_h0   = (float*)(ws + alloc(NTT * HC * 4));
    float* t_as0  = (float*)(ws + alloc(NTT * NHEAD * 4));
    float* t_ad0  = (float*)(ws + alloc(NTT * NHEAD * 4));
    float* t_ae0  = (float*)(ws + alloc(NRR * NHEAD * 4));
    float* t_ae1  = (float*)(ws + alloc(NRR * NHEAD * 4));
    u16*   x1b    = (u16*)(ws + alloc((size_t)N_NODES * CDIM * 2));
    float* asrc1  = (float*)(ws + alloc((size_t)N_NODES * NHEAD * 4));
    float* adst1  = (float*)(ws + alloc((size_t)N_NODES * NHEAD * 4));
    u16*   h1b    = (u16*)(ws + alloc((size_t)N_NODES * HC * 2));
    float* x2     = (float*)(ws + alloc((size_t)N_NODES * CDIM * 4));

    int wsMB = (int)(ws_size >> 20); if (wsMB > 1023) wsMB = 1023;
    int hostA = 0, hostB = 0;
    if (mc < 0) { hostA |= 1; hostB = (n_in != 22) ? (n_in < 1023 ? n_in : 1023) : 0; }
    if (mc >= 0 && off > ws_size) hostA |= 2;

    if (hostA == 0) {
        const int* P = cand_pos[mc];
        const int*   node_type  = (const int*)d_in[P[0]];
        const int*   edge_type  = (const int*)d_in[P[1]];
        const int*   edge_index = (const int*)d_in[P[2]];
        const int*   batch      = (const int*)d_in[P[3]];
        const float* node_emb   = (const float*)d_in[P[4]];
        const float* edge_emb   = (const float*)d_in[P[5]];
        const float* W0  = (const float*)d_in[P[6]];
        const float* We0 = (const float*)d_in[P[7]];
        const float* as0 = (const float*)d_in[P[8]];
        const float* ad0 = (const float*)d_in[P[9]];
        const float* ae0 = (const float*)d_in[P[10]];
        const float* b0  = (const float*)d_in[P[11]];
        const float* W1  = (const float*)d_in[P[12]];
        const float* We1 = (const float*)d_in[P[13]];
        const float* as1 = (const float*)d_in[P[14]];
        const float* ad1 = (const float*)d_in[P[15]];
        const float* ae1 = (const float*)d_in[P[16]];
        const float* b1  = (const float*)d_in[P[17]];
        const float* cw1 = (const float*)d_in[P[18]];
        const float* cb1 = (const float*)d_in[P[19]];
        const float* cw2 = (const float*)d_in[P[20]];
        const float* cb2 = (const float*)d_in[P[21]];

        int zero_elems = (int)(zero_bytes / 4);
        k_zero<<<(zero_elems + 255) / 256, 256, 0, stream>>>((float*)ws, zero_elems);
        k_tables<<<1, 256, 0, stream>>>(node_emb, edge_emb, W0, We0, as0, ad0, ae0,
                                        We1, ae1,
                                        t_h0, t_as0, t_ad0, t_ae0, t_ae1);
        k_count<<<(N_EDGES + 255) / 256, 256, 0, stream>>>(edge_index, deg4,
                                                           batch, goffs);
        k_scan1<<<NBLK_SCAN, 256, 0, stream>>>(deg4, deg, blksum);
        k_scan3<<<NBLK_SCAN, 256, 0, stream>>>(deg, blksum, offs, cursor);
        k_scatter<<<(N_EDGES + 255) / 256, 256, 0, stream>>>(edge_index, edge_type,
                                                             node_type, cursor, csrp);
        k_layer0<<<(N_NODES * 64) / 256, 256, 0, stream>>>(
            node_type, offs, csrp, t_h0, t_as0, t_ad0, t_ae0, b0, x1b);
        k_gemm1<<<625, 256, 0, stream>>>(
            x1b, W1, as1, ad1, h1b, asrc1, adst1);
        k_agg1<<<(N_NODES * 64) / 256, 256, 0, stream>>>(
            offs, csrp, h1b, asrc1, adst1, t_ae1, b1, x2);
        k_poolcls<<<N_GRAPH, 256, 0, stream>>>(
            x2, goffs, cw1, cb1, cw2, cb2, (float*)d_out, wsMB, offs, csrp, W1);
    } else {
        int code = (hostA << 20) | (wsMB << 10) | (hostB > 1023 ? 1023 : hostB);
        k_fault<<<1, 64, 0, stream>>>(code, (float*)d_out);
    }
}

// Round 16
// 359.083 us; speedup vs baseline: 1.0651x; 1.0651x over previous
//
#include <hip/hip_runtime.h>
#include <hip/hip_bf16.h>

#define N_NODES 50000
#define N_EDGES 800000
#define N_GRAPH 64
#define NHEAD 4
#define CDIM 64
#define HC 256      // NHEAD*CDIM
#define NTT 8
#define NRR 6
#define EDIMM 16
#define SCAN_CHUNK 1024
#define NBLK_SCAN ((N_NODES + SCAN_CHUNK - 1) / SCAN_CHUNK)   // 49

typedef unsigned short u16;
typedef __attribute__((ext_vector_type(8))) short bf8;   // 8 bf16 (4 VGPRs)
typedef __attribute__((ext_vector_type(4))) float f4;    // MFMA acc

__device__ __forceinline__ float eluf(float v) { return v > 0.f ? v : expm1f(v); }
__device__ __forceinline__ float u2f(u16 u) {
    union { float f; unsigned int i; } c; c.i = ((unsigned int)u) << 16; return c.f;
}
__device__ __forceinline__ u16 f2u(float f) {
    union { float f; unsigned int i; } c; c.f = f;
    unsigned int i = c.i;
    return (u16)((i + 0x7FFFu + ((i >> 16) & 1u)) >> 16);
}
__device__ __forceinline__ float lrelu(float v) { return v > 0.f ? v : 0.2f * v; }

__global__ __launch_bounds__(256) void k_zero(float* __restrict__ p, int n)
{
    int i = blockIdx.x * 256 + threadIdx.x;
    if (i < n) p[i] = 0.f;
}

// ---------------------------------------------------------------------------
// Tiny tables — PARALLELIZED: 14 blocks (8 node types + 6 relations), each
// self-contained. Was 1 serial block (~15 us); now ~2 us.
// ---------------------------------------------------------------------------
__global__ __launch_bounds__(256) void k_tables(
    const float* __restrict__ node_emb, const float* __restrict__ edge_emb,
    const float* __restrict__ W0, const float* __restrict__ We0,
    const float* __restrict__ as0, const float* __restrict__ ad0,
    const float* __restrict__ ae0, const float* __restrict__ We1,
    const float* __restrict__ ae1,
    float* __restrict__ t_h0, float* __restrict__ t_as0,
    float* __restrict__ t_ad0, float* __restrict__ t_ae0,
    float* __restrict__ t_ae1)
{
    __shared__ float srow[HC];
    __shared__ float srow2[HC];
    int tid = threadIdx.x;
    int b = blockIdx.x;
    if (b < NTT) {            // node type b: t_h0 row + as0/ad0 dots
        int t = b;
        float acc = 0.f;
        #pragma unroll 8
        for (int k = 0; k < CDIM; k++)
            acc += node_emb[t * CDIM + k] * W0[k * HC + tid];
        srow[tid] = acc;
        t_h0[t * HC + tid] = acc;
        __syncthreads();
        if (tid < NHEAD) {
            int h = tid;
            float a = 0.f, d = 0.f;
            for (int c = 0; c < CDIM; c++) {
                float hv = srow[h * CDIM + c];
                a += hv * as0[h * CDIM + c];
                d += hv * ad0[h * CDIM + c];
            }
            t_as0[t * NHEAD + h] = a;
            t_ad0[t * NHEAD + h] = d;
        }
    } else {                  // relation r: ae0/ae1 dots (both layers)
        int r = b - NTT;
        float a0 = 0.f, a1 = 0.f;
        #pragma unroll
        for (int k = 0; k < EDIMM; k++) {
            float ev = edge_emb[r * EDIMM + k];
            a0 += ev * We0[k * HC + tid];
            a1 += ev * We1[k * HC + tid];
        }
        srow[tid] = a0;
        srow2[tid] = a1;
        __syncthreads();
        if (tid < NHEAD) {
            int h = tid;
            float s0 = 0.f, s1 = 0.f;
            for (int c = 0; c < CDIM; c++) {
                s0 += srow[h * CDIM + c] * ae0[h * CDIM + c];
                s1 += srow2[h * CDIM + c] * ae1[h * CDIM + c];
            }
            t_ae0[r * NHEAD + h] = s0;
            t_ae1[r * NHEAD + h] = s1;
        }
    }
}

// ---------------------------------------------------------------------------
// Degree count (4-way privatized) + fused goffs boundary detection
// ---------------------------------------------------------------------------
__global__ __launch_bounds__(256) void k_count(
    const int* __restrict__ edge_index, int* __restrict__ deg4,
    const int* __restrict__ batch, int* __restrict__ goffs)
{
    int i = blockIdx.x * 256 + threadIdx.x;
    if (i < N_EDGES)
        atomicAdd(&deg4[(blockIdx.x & 3) * N_NODES + edge_index[N_EDGES + i]], 1);
    if (i < N_NODES) {
        int bi = batch[i];
        int bp = (i == 0) ? -1 : batch[i - 1];
        for (int g = bp + 1; g <= bi; g++) goffs[g] = i;
        if (i == N_NODES - 1)
            for (int g = bi + 1; g <= N_GRAPH; g++) goffs[g] = N_NODES;
    }
}

__global__ __launch_bounds__(256) void k_scan1(
    const int* __restrict__ deg4, int* __restrict__ deg, int* __restrict__ blksum)
{
    __shared__ int s[256];
    int b = blockIdx.x, tid = threadIdx.x;
    int base = b * SCAN_CHUNK + tid * 4;
    int t = 0;
    #pragma unroll
    for (int k = 0; k < 4; k++) {
        int i = base + k;
        if (i < N_NODES) {
            int d = deg4[i] + deg4[N_NODES + i] + deg4[2 * N_NODES + i]
                  + deg4[3 * N_NODES + i];
            deg[i] = d;
            t += d;
        }
    }
    s[tid] = t;
    __syncthreads();
    for (int off = 128; off > 0; off >>= 1) {
        if (tid < off) s[tid] += s[tid + off];
        __syncthreads();
    }
    if (tid == 0) blksum[b] = s[0];
}

__global__ __launch_bounds__(256) void k_scan3(
    const int* __restrict__ deg, const int* __restrict__ blksum,
    int* __restrict__ offs, int* __restrict__ cursor)
{
    __shared__ int s[256];
    __shared__ int sbase;
    int b = blockIdx.x, tid = threadIdx.x;
    if (tid < 64) {
        int v = (tid < b) ? blksum[tid] : 0;
        #pragma unroll
        for (int d = 32; d >= 1; d >>= 1) v += __shfl_xor(v, d);
        if (tid == 0) sbase = v;
    }
    int base = b * SCAN_CHUNK + tid * 4;
    int d4[4]; int t = 0;
    #pragma unroll
    for (int k = 0; k < 4; k++) {
        int i = base + k;
        d4[k] = (i < N_NODES) ? deg[i] : 0;
        t += d4[k];
    }
    s[tid] = t;
    __syncthreads();
    for (int off = 1; off < 256; off <<= 1) {
        int v = (tid >= off) ? s[tid - off] : 0;
        __syncthreads();
        s[tid] += v;
        __syncthreads();
    }
    int excl = sbase + s[tid] - t;
    #pragma unroll
    for (int k = 0; k < 4; k++) {
        int i = base + k;
        if (i < N_NODES) { offs[i] = excl; cursor[i] = excl; }
        excl += d4[k];
    }
    if (b == NBLK_SCAN - 1 && tid == 255) offs[N_NODES] = excl;
}

__global__ __launch_bounds__(256) void k_scatter(
    const int* __restrict__ edge_index, const int* __restrict__ edge_type,
    const int* __restrict__ node_type, int* __restrict__ cursor,
    int* __restrict__ csrp)
{
    int e = blockIdx.x * 256 + threadIdx.x;
    if (e < N_EDGES) {
        int d  = edge_index[N_EDGES + e];
        int s  = edge_index[e];
        int et = edge_type[e];
        int ts = node_type[s];
        int pos = atomicAdd(&cursor[d], 1);
        csrp[pos] = s | (et << 16) | (ts << 19);
    }
}

// ---------------------------------------------------------------------------
// Layer-0 edge phase (R14-proven form: independent lanes, batch-4 + tail).
// Writes x1 bf16 (MFMA A operand).
// ---------------------------------------------------------------------------
__global__ __launch_bounds__(256) void k_layer0(
    const int* __restrict__ node_type, const int* __restrict__ offs,
    const int* __restrict__ csrp,
    const float* __restrict__ t_h0, const float* __restrict__ t_as0,
    const float* __restrict__ t_ad0, const float* __restrict__ t_ae0,
    const float* __restrict__ b0, u16* __restrict__ x1b)
{
    __shared__ float s_h0[NTT * HC];                 // 8 KB
    __shared__ float s_as[NTT * NHEAD], s_ad[NTT * NHEAD], s_ae[NRR * NHEAD];
    __shared__ float s_b0[CDIM];

    int tid = threadIdx.x;
    for (int i = tid; i < NTT * HC; i += 256) s_h0[i] = t_h0[i];
    if (tid < NTT * NHEAD) { s_as[tid] = t_as0[tid]; s_ad[tid] = t_ad0[tid]; }
    if (tid < NRR * NHEAD) s_ae[tid] = t_ae0[tid];
    if (tid < CDIM) s_b0[tid] = b0[tid];
    __syncthreads();

    int n = (blockIdx.x * 256 + tid) >> 6;
    int lane = tid & 63;
    int h = lane >> 4;
    int cq = (lane & 15) << 2;

    int tn = node_type[n];
    float adst = s_ad[tn * NHEAD + h];
    int e0 = offs[n], e1 = offs[n + 1];
    int efull = e0 + ((e1 - e0) & ~3);
    float ax = 0.f, ay = 0.f, az = 0.f, aw = 0.f, den = 0.f;
    for (int i = e0; i < efull; i += 4) {
        int rA = csrp[i],     rB = csrp[i + 1];
        int rC = csrp[i + 2], rD = csrp[i + 3];
        int tA = rA >> 19, tB = rB >> 19, tC = rC >> 19, tD = rD >> 19;
        int eA = (rA >> 16) & 7, eB = (rB >> 16) & 7;
        int eC = (rC >> 16) & 7, eD = (rD >> 16) & 7;
        float pA = __expf(lrelu(s_as[tA * NHEAD + h] + adst + s_ae[eA * NHEAD + h]));
        float pB = __expf(lrelu(s_as[tB * NHEAD + h] + adst + s_ae[eB * NHEAD + h]));
        float pC = __expf(lrelu(s_as[tC * NHEAD + h] + adst + s_ae[eC * NHEAD + h]));
        float pD = __expf(lrelu(s_as[tD * NHEAD + h] + adst + s_ae[eD * NHEAD + h]));
        den += pA + pB + pC + pD;
        const float4 vA = *(const float4*)(s_h0 + tA * HC + h * CDIM + cq);
        const float4 vB = *(const float4*)(s_h0 + tB * HC + h * CDIM + cq);
        const float4 vC = *(const float4*)(s_h0 + tC * HC + h * CDIM + cq);
        const float4 vD = *(const float4*)(s_h0 + tD * HC + h * CDIM + cq);
        ax += pA * vA.x + pB * vB.x + pC * vC.x + pD * vD.x;
        ay += pA * vA.y + pB * vB.y + pC * vC.y + pD * vD.y;
        az += pA * vA.z + pB * vB.z + pC * vC.z + pD * vD.z;
        aw += pA * vA.w + pB * vB.w + pC * vC.w + pD * vD.w;
    }
    for (int i = efull; i < e1; i++) {
        int r = csrp[i];
        int ts = r >> 19, et = (r >> 16) & 7;
        float p = __expf(lrelu(s_as[ts * NHEAD + h] + adst + s_ae[et * NHEAD + h]));
        den += p;
        const float4 v = *(const float4*)(s_h0 + ts * HC + h * CDIM + cq);
        ax += p * v.x; ay += p * v.y; az += p * v.z; aw += p * v.w;
    }
    float inv = 0.25f / (den + 1e-16f);
    ax *= inv; ay *= inv; az *= inv; aw *= inv;
    ax += __shfl_xor(ax, 16); ax += __shfl_xor(ax, 32);
    ay += __shfl_xor(ay, 16); ay += __shfl_xor(ay, 32);
    az += __shfl_xor(az, 16); az += __shfl_xor(az, 32);
    aw += __shfl_xor(aw, 16); aw += __shfl_xor(aw, 32);
    if (lane < 16) {
        ushort4 o;
        o.x = f2u(eluf(ax + s_b0[cq + 0]));
        o.y = f2u(eluf(ay + s_b0[cq + 1]));
        o.z = f2u(eluf(az + s_b0[cq + 2]));
        o.w = f2u(eluf(aw + s_b0[cq + 3]));
        *(ushort4*)(x1b + (size_t)n * CDIM + cq) = o;
    }
}

// ---------------------------------------------------------------------------
// h1 = x1 @ W1 via MFMA 16x16x32 bf16 (layouts HW-verified R13).
// ---------------------------------------------------------------------------
__global__ __launch_bounds__(256) void k_gemm1(
    const u16* __restrict__ x1b, const float* __restrict__ W1,
    const float* __restrict__ as1, const float* __restrict__ ad1,
    u16* __restrict__ h1b, float* __restrict__ asrc1, float* __restrict__ adst1)
{
    __shared__ u16 ht[16 * HC];   // 8 KB
    int tid = threadIdx.x;
    int lane = tid & 63, wv = tid >> 6;
    int quad = lane >> 4, c16 = lane & 15;

    bf8 bf[4][2];
    float sv[4], dv[4];
    #pragma unroll
    for (int t = 0; t < 4; t++) {
        int col = wv * 64 + t * 16 + c16;
        sv[t] = as1[col];
        dv[t] = ad1[col];
        #pragma unroll
        for (int kf = 0; kf < 2; kf++)
            #pragma unroll
            for (int j = 0; j < 8; j++)
                bf[t][kf][j] = (short)f2u(W1[(kf * 32 + quad * 8 + j) * HC + col]);
    }

    for (int it = 0; it < 5; it++) {
        int nt = it * 625 + blockIdx.x;
        const bf8 a0 = *(const bf8*)(x1b + (size_t)(nt * 16 + c16) * CDIM + quad * 8);
        const bf8 a1 = *(const bf8*)(x1b + (size_t)(nt * 16 + c16) * CDIM + 32 + quad * 8);
        f4 acc[4];
        #pragma unroll
        for (int t = 0; t < 4; t++) {
            acc[t] = (f4){0.f, 0.f, 0.f, 0.f};
            acc[t] = __builtin_amdgcn_mfma_f32_16x16x32_bf16(a0, bf[t][0], acc[t], 0, 0, 0);
            acc[t] = __builtin_amdgcn_mfma_f32_16x16x32_bf16(a1, bf[t][1], acc[t], 0, 0, 0);
        }
        float rs[4] = {0.f, 0.f, 0.f, 0.f}, rd[4] = {0.f, 0.f, 0.f, 0.f};
        #pragma unroll
        for (int t = 0; t < 4; t++)
            #pragma unroll
            for (int reg = 0; reg < 4; reg++) {
                float v = acc[t][reg];
                rs[reg] += v * sv[t];
                rd[reg] += v * dv[t];
                ht[(quad * 4 + reg) * HC + wv * 64 + t * 16 + c16] = f2u(v);
            }
        #pragma unroll
        for (int reg = 0; reg < 4; reg++)
            #pragma unroll
            for (int d = 1; d < 16; d <<= 1) {
                rs[reg] += __shfl_xor(rs[reg], d);
                rd[reg] += __shfl_xor(rd[reg], d);
            }
        if (c16 == 0) {
            #pragma unroll
            for (int reg = 0; reg < 4; reg++) {
                int n = nt * 16 + quad * 4 + reg;
                asrc1[n * NHEAD + wv] = rs[reg];
                adst1[n * NHEAD + wv] = rd[reg];
            }
        }
        __syncthreads();
        const uint4* src = (const uint4*)ht;
        uint4* dst = (uint4*)(h1b + (size_t)nt * 16 * HC);
        dst[tid] = src[tid];
        dst[tid + 256] = src[tid + 256];
        __syncthreads();
    }
}

// ---------------------------------------------------------------------------
// Layer 1 aggregation + ELU -> x2 (R14-proven: independent lanes, batch-8).
// ---------------------------------------------------------------------------
__global__ __launch_bounds__(256) void k_agg1(
    const int* __restrict__ offs, const int* __restrict__ csrp,
    const u16* __restrict__ h1b, const float* __restrict__ asrc1,
    const float* __restrict__ adst1, const float* __restrict__ t_ae1,
    const float* __restrict__ b1, float* __restrict__ x2)
{
    __shared__ float s_ae[NRR * NHEAD];
    if (threadIdx.x < NRR * NHEAD) s_ae[threadIdx.x] = t_ae1[threadIdx.x];
    __syncthreads();

    int n = (blockIdx.x * 256 + threadIdx.x) >> 6;
    int lane = threadIdx.x & 63;
    int h = lane >> 4;
    int cq = (lane & 15) << 2;
    float adst = adst1[n * NHEAD + h];
    int e0 = offs[n], e1 = offs[n + 1];
    int efull = e0 + ((e1 - e0) & ~7);

    float ax = 0.f, ay = 0.f, az = 0.f, aw = 0.f, den = 0.f;
    for (int i = e0; i < efull; i += 8) {
        int rec[8], s[8], et[8];
        #pragma unroll
        for (int k = 0; k < 8; k++) rec[k] = csrp[i + k];
        #pragma unroll
        for (int k = 0; k < 8; k++) { s[k] = rec[k] & 0xFFFF; et[k] = (rec[k] >> 16) & 7; }
        float asv[8];
        ushort4 hv[8];
        #pragma unroll
        for (int k = 0; k < 8; k++) asv[k] = asrc1[s[k] * NHEAD + h];
        #pragma unroll
        for (int k = 0; k < 8; k++)
            hv[k] = *(const ushort4*)(h1b + (size_t)s[k] * HC + h * CDIM + cq);
        #pragma unroll
        for (int k = 0; k < 8; k++) {
            float p = __expf(lrelu(asv[k] + adst + s_ae[et[k] * NHEAD + h]));
            den += p;
            ax += p * u2f(hv[k].x);
            ay += p * u2f(hv[k].y);
            az += p * u2f(hv[k].z);
            aw += p * u2f(hv[k].w);
        }
    }
    for (int i = efull; i < e1; i++) {
        int rec = csrp[i];
        int s = rec & 0xFFFF, et = (rec >> 16) & 7;
        float p = __expf(lrelu(asrc1[s * NHEAD + h] + adst + s_ae[et * NHEAD + h]));
        den += p;
        ushort4 hv = *(const ushort4*)(h1b + (size_t)s * HC + h * CDIM + cq);
        ax += p * u2f(hv.x); ay += p * u2f(hv.y);
        az += p * u2f(hv.z); aw += p * u2f(hv.w);
    }
    float inv = 0.25f / (den + 1e-16f);
    ax *= inv; ay *= inv; az *= inv; aw *= inv;
    ax += __shfl_xor(ax, 16); ax += __shfl_xor(ax, 32);
    ay += __shfl_xor(ay, 16); ay += __shfl_xor(ay, 32);
    az += __shfl_xor(az, 16); az += __shfl_xor(az, 32);
    aw += __shfl_xor(aw, 16); aw += __shfl_xor(aw, 32);
    if (lane < 16) {
        float4 o;
        o.x = eluf(ax + b1[cq + 0]);
        o.y = eluf(ay + b1[cq + 1]);
        o.z = eluf(az + b1[cq + 2]);
        o.w = eluf(aw + b1[cq + 3]);
        *(float4*)(x2 + (size_t)n * CDIM + cq) = o;
    }
}

// ---------------------------------------------------------------------------
// FUSED mean-pool + classifier (+ diag in block 0, fires only on fault)
// ---------------------------------------------------------------------------
__global__ __launch_bounds__(256) void k_poolcls(
    const float* __restrict__ x2, const int* __restrict__ goffs,
    const float* __restrict__ cw1, const float* __restrict__ cb1,
    const float* __restrict__ cw2, const float* __restrict__ cb2,
    float* __restrict__ out, int wsMB,
    const int* __restrict__ offs, const int* __restrict__ csrp,
    const float* __restrict__ W1)
{
    __shared__ float part[4][CDIM];
    __shared__ float gsh[CDIM];
    int g = blockIdx.x;
    int ch = threadIdx.x & 63, rg = threadIdx.x >> 6;
    int gs = goffs[g], ge = goffs[g + 1];
    float acc = 0.f;
    for (int r = gs + rg; r < ge; r += 4)
        acc += x2[(size_t)r * CDIM + ch];
    part[rg][ch] = acc;
    __syncthreads();
    if (threadIdx.x < CDIM) {
        float s = part[0][ch] + part[1][ch] + part[2][ch] + part[3][ch];
        int c = ge - gs;
        gsh[ch] = s / (float)(c > 1 ? c : 1);
    }
    __syncthreads();
    if (threadIdx.x < 64) {
        int j = threadIdx.x;
        float a = cb1[j];
        #pragma unroll
        for (int k = 0; k < CDIM; k++) a += gsh[k] * cw1[k * CDIM + j];
        float hid = a > 0.f ? a : 0.f;
        float o0 = hid * cw2[j * 2 + 0];
        float o1 = hid * cw2[j * 2 + 1];
        #pragma unroll
        for (int d = 32; d >= 1; d >>= 1) {
            o0 += __shfl_xor(o0, d);
            o1 += __shfl_xor(o1, d);
        }
        if (j == 0) {
            out[g * 2 + 0] = o0 + cb2[0];
            out[g * 2 + 1] = o1 + cb2[1];
        }
    }
    if (g == 0) {
        __shared__ int simpl, soob, sA;
        if (threadIdx.x == 0) { simpl = 0; soob = 0; sA = 0; }
        __syncthreads();
        if (threadIdx.x == 0 && offs[N_NODES] != N_EDGES) atomicOr(&sA, 4);
        float v = W1[threadIdx.x];
        if (!(fabsf(v) < 100.f)) atomicAdd(&simpl, 1);
        int r = csrp[threadIdx.x];
        if ((r & 0xFFFF) >= N_NODES || (r >> 22) != 0 || r < 0) atomicAdd(&soob, 1);
        __syncthreads();
        if (threadIdx.x == 0) {
            int A = sA;
            if (simpl > 10) A |= 8;
            int B = soob > 1023 ? 1023 : soob;
            if (A | B) out[0] = (float)((A << 20) | (wsMB << 10) | B);
        }
    }
}

__global__ void k_fault(int code, float* __restrict__ out)
{
    if (threadIdx.x == 0 && blockIdx.x == 0) out[0] = (float)code;
}

// ---------------------------------------------------------------------------
extern "C" void kernel_launch(void* const* d_in, const int* in_sizes, int n_in,
                              void* d_out, int out_size, void* d_ws, size_t ws_size,
                              hipStream_t stream) {
    static const int rsize[22] = {50000, 800000, 1600000, 50000, 512, 96,
                                  16384, 4096, 256, 256, 256, 64,
                                  16384, 4096, 256, 256, 256, 64,
                                  4096, 64, 128, 2};
    static const int cand_pos[3][22] = {
        {21,19,18,12,20,17,0,2,8,4,6,10,1,3,9,5,7,11,15,13,16,14},   // ASCII sorted (R7)
        {0,1,2,3,4,5,6,7,8,9,10,11,12,13,14,15,16,17,18,19,20,21},   // dict order
        {17,15,14,8,16,13,18,20,4,0,2,6,19,21,5,1,3,7,11,9,12,10},   // case-insens
    };
    int mc = -1;
    if (n_in == 22) {
        for (int c = 0; c < 3 && mc < 0; c++) {
            bool ok = true;
            for (int r = 0; r < 22; r++)
                if (in_sizes[cand_pos[c][r]] != rsize[r]) { ok = false; break; }
            if (ok) mc = c;
        }
    }

    char* ws = (char*)d_ws;
    size_t off = 0;
    auto alloc = [&](size_t b) { size_t r = off; off += (b + 255) & ~(size_t)255; return r; };
    int*   deg4   = (int*)(ws + alloc((size_t)4 * N_NODES * 4));   // zeroed
    size_t zero_bytes = off;
    int*   deg    = (int*)(ws + alloc(N_NODES * 4));
    int*   blksum = (int*)(ws + alloc(NBLK_SCAN * 4));
    int*   offs   = (int*)(ws + alloc((N_NODES + 1) * 4));
    int*   cursor = (int*)(ws + alloc(N_NODES * 4));
    int*   csrp   = (int*)(ws + alloc(N_EDGES * 4));
    int*   goffs  = (int*)(ws + alloc((N_GRAPH + 1) * 4));
    float* t_h0   = (float*)(ws + alloc(NTT * HC * 4));
    float* t_as0  = (float*)(ws + alloc(NTT * NHEAD * 4));
    float* t_ad0  = (float*)(ws + alloc(NTT * NHEAD * 4));
    float* t_ae0  = (float*)(ws + alloc(NRR * NHEAD * 4));
    float* t_ae1  = (float*)(ws + alloc(NRR * NHEAD * 4));
    u16*   x1b    = (u16*)(ws + alloc((size_t)N_NODES * CDIM * 2));
    float* asrc1  = (float*)(ws + alloc((size_t)N_NODES * NHEAD * 4));
    float* adst1  = (float*)(ws + alloc((size_t)N_NODES * NHEAD * 4));
    u16*   h1b    = (u16*)(ws + alloc((size_t)N_NODES * HC * 2));
    float* x2     = (float*)(ws + alloc((size_t)N_NODES * CDIM * 4));

    int wsMB = (int)(ws_size >> 20); if (wsMB > 1023) wsMB = 1023;
    int hostA = 0, hostB = 0;
    if (mc < 0) { hostA |= 1; hostB = (n_in != 22) ? (n_in < 1023 ? n_in : 1023) : 0; }
    if (mc >= 0 && off > ws_size) hostA |= 2;

    if (hostA == 0) {
        const int* P = cand_pos[mc];
        const int*   node_type  = (const int*)d_in[P[0]];
        const int*   edge_type  = (const int*)d_in[P[1]];
        const int*   edge_index = (const int*)d_in[P[2]];
        const int*   batch      = (const int*)d_in[P[3]];
        const float* node_emb   = (const float*)d_in[P[4]];
        const float* edge_emb   = (const float*)d_in[P[5]];
        const float* W0  = (const float*)d_in[P[6]];
        const float* We0 = (const float*)d_in[P[7]];
        const float* as0 = (const float*)d_in[P[8]];
        const float* ad0 = (const float*)d_in[P[9]];
        const float* ae0 = (const float*)d_in[P[10]];
        const float* b0  = (const float*)d_in[P[11]];
        const float* W1  = (const float*)d_in[P[12]];
        const float* We1 = (const float*)d_in[P[13]];
        const float* as1 = (const float*)d_in[P[14]];
        const float* ad1 = (const float*)d_in[P[15]];
        const float* ae1 = (const float*)d_in[P[16]];
        const float* b1  = (const float*)d_in[P[17]];
        const float* cw1 = (const float*)d_in[P[18]];
        const float* cb1 = (const float*)d_in[P[19]];
        const float* cw2 = (const float*)d_in[P[20]];
        const float* cb2 = (const float*)d_in[P[21]];

        int zero_elems = (int)(zero_bytes / 4);
        k_zero<<<(zero_elems + 255) / 256, 256, 0, stream>>>((float*)ws, zero_elems);
        k_tables<<<NTT + NRR, 256, 0, stream>>>(node_emb, edge_emb, W0, We0, as0,
                                                ad0, ae0, We1, ae1,
                                                t_h0, t_as0, t_ad0, t_ae0, t_ae1);
        k_count<<<(N_EDGES + 255) / 256, 256, 0, stream>>>(edge_index, deg4,
                                                           batch, goffs);
        k_scan1<<<NBLK_SCAN, 256, 0, stream>>>(deg4, deg, blksum);
        k_scan3<<<NBLK_SCAN, 256, 0, stream>>>(deg, blksum, offs, cursor);
        k_scatter<<<(N_EDGES + 255) / 256, 256, 0, stream>>>(edge_index, edge_type,
                                                             node_type, cursor, csrp);
        k_layer0<<<(N_NODES * 64) / 256, 256, 0, stream>>>(
            node_type, offs, csrp, t_h0, t_as0, t_ad0, t_ae0, b0, x1b);
        k_gemm1<<<625, 256, 0, stream>>>(
            x1b, W1, as1, ad1, h1b, asrc1, adst1);
        k_agg1<<<(N_NODES * 64) / 256, 256, 0, stream>>>(
            offs, csrp, h1b, asrc1, adst1, t_ae1, b1, x2);
        k_poolcls<<<N_GRAPH, 256, 0, stream>>>(
            x2, goffs, cw1, cb1, cw2, cb2, (float*)d_out, wsMB, offs, csrp, W1);
    } else {
        int code = (hostA << 20) | (wsMB << 10) | (hostB > 1023 ? 1023 : hostB);
        k_fault<<<1, 64, 0, stream>>>(code, (float*)d_out);
    }
}

// Round 17
// 347.883 us; speedup vs baseline: 1.0994x; 1.0322x over previous
//
#include <hip/hip_runtime.h>
#include <hip/hip_bf16.h>

#define N_NODES 50000
#define N_EDGES 800000
#define N_GRAPH 64
#define NHEAD 4
#define CDIM 64
#define HC 256      // NHEAD*CDIM
#define NTT 8
#define NRR 6
#define EDIMM 16
#define SCAN_CHUNK 1024
#define NBLK_SCAN ((N_NODES + SCAN_CHUNK - 1) / SCAN_CHUNK)   // 49
#define H1SCALE 1024.f      // fp8 encode scale (values ~0.006 -> ~6, e4m3 normal)

typedef unsigned short u16;
typedef unsigned char u8;
typedef __attribute__((ext_vector_type(8))) short bf8;   // 8 bf16 (4 VGPRs)
typedef __attribute__((ext_vector_type(4))) float f4;    // MFMA acc
typedef __attribute__((ext_vector_type(2))) float v2f;

__device__ __forceinline__ float eluf(float v) { return v > 0.f ? v : expm1f(v); }
__device__ __forceinline__ u16 f2u(float f) {
    union { float f; unsigned int i; } c; c.f = f;
    unsigned int i = c.i;
    return (u16)((i + 0x7FFFu + ((i >> 16) & 1u)) >> 16);
}
__device__ __forceinline__ float lrelu(float v) { return v > 0.f ? v : 0.2f * v; }
__device__ __forceinline__ u8 f2fp8(float v) {
    return (u8)(__builtin_amdgcn_cvt_pk_fp8_f32(v, 0.f, 0, false) & 0xFF);
}

__global__ __launch_bounds__(256) void k_zero(float* __restrict__ p, int n)
{
    int i = blockIdx.x * 256 + threadIdx.x;
    if (i < n) p[i] = 0.f;
}

// ---------------------------------------------------------------------------
// Tiny tables — 14 parallel blocks (8 node types + 6 relations)
// ---------------------------------------------------------------------------
__global__ __launch_bounds__(256) void k_tables(
    const float* __restrict__ node_emb, const float* __restrict__ edge_emb,
    const float* __restrict__ W0, const float* __restrict__ We0,
    const float* __restrict__ as0, const float* __restrict__ ad0,
    const float* __restrict__ ae0, const float* __restrict__ We1,
    const float* __restrict__ ae1,
    float* __restrict__ t_h0, float* __restrict__ t_as0,
    float* __restrict__ t_ad0, float* __restrict__ t_ae0,
    float* __restrict__ t_ae1)
{
    __shared__ float srow[HC];
    __shared__ float srow2[HC];
    int tid = threadIdx.x;
    int b = blockIdx.x;
    if (b < NTT) {
        int t = b;
        float acc = 0.f;
        #pragma unroll 8
        for (int k = 0; k < CDIM; k++)
            acc += node_emb[t * CDIM + k] * W0[k * HC + tid];
        srow[tid] = acc;
        t_h0[t * HC + tid] = acc;
        __syncthreads();
        if (tid < NHEAD) {
            int h = tid;
            float a = 0.f, d = 0.f;
            for (int c = 0; c < CDIM; c++) {
                float hv = srow[h * CDIM + c];
                a += hv * as0[h * CDIM + c];
                d += hv * ad0[h * CDIM + c];
            }
            t_as0[t * NHEAD + h] = a;
            t_ad0[t * NHEAD + h] = d;
        }
    } else {
        int r = b - NTT;
        float a0 = 0.f, a1 = 0.f;
        #pragma unroll
        for (int k = 0; k < EDIMM; k++) {
            float ev = edge_emb[r * EDIMM + k];
            a0 += ev * We0[k * HC + tid];
            a1 += ev * We1[k * HC + tid];
        }
        srow[tid] = a0;
        srow2[tid] = a1;
        __syncthreads();
        if (tid < NHEAD) {
            int h = tid;
            float s0 = 0.f, s1 = 0.f;
            for (int c = 0; c < CDIM; c++) {
                s0 += srow[h * CDIM + c] * ae0[h * CDIM + c];
                s1 += srow2[h * CDIM + c] * ae1[h * CDIM + c];
            }
            t_ae0[r * NHEAD + h] = s0;
            t_ae1[r * NHEAD + h] = s1;
        }
    }
}

// Layer-0 attention probability table: t_exp[tn*192 + et*32 + ts*4 + h]
__global__ __launch_bounds__(256) void k_exptab(
    const float* __restrict__ t_as0, const float* __restrict__ t_ad0,
    const float* __restrict__ t_ae0, float* __restrict__ t_exp)
{
    for (int idx = threadIdx.x; idx < NTT * NRR * NTT * NHEAD; idx += 256) {
        int tn = idx / 192;
        int rem = idx - tn * 192;
        int et = rem >> 5;
        int ts = (rem >> 2) & 7;
        int h = rem & 3;
        float lg = t_as0[ts * NHEAD + h] + t_ad0[tn * NHEAD + h]
                 + t_ae0[et * NHEAD + h];
        t_exp[idx] = __expf(lrelu(lg));
    }
}

// ---------------------------------------------------------------------------
// Degree count (4-way privatized) + fused goffs boundary detection
// ---------------------------------------------------------------------------
__global__ __launch_bounds__(256) void k_count(
    const int* __restrict__ edge_index, int* __restrict__ deg4,
    const int* __restrict__ batch, int* __restrict__ goffs)
{
    int i = blockIdx.x * 256 + threadIdx.x;
    if (i < N_EDGES)
        atomicAdd(&deg4[(blockIdx.x & 3) * N_NODES + edge_index[N_EDGES + i]], 1);
    if (i < N_NODES) {
        int bi = batch[i];
        int bp = (i == 0) ? -1 : batch[i - 1];
        for (int g = bp + 1; g <= bi; g++) goffs[g] = i;
        if (i == N_NODES - 1)
            for (int g = bi + 1; g <= N_GRAPH; g++) goffs[g] = N_NODES;
    }
}

__global__ __launch_bounds__(256) void k_scan1(
    const int* __restrict__ deg4, int* __restrict__ deg, int* __restrict__ blksum)
{
    __shared__ int s[256];
    int b = blockIdx.x, tid = threadIdx.x;
    int base = b * SCAN_CHUNK + tid * 4;
    int t = 0;
    #pragma unroll
    for (int k = 0; k < 4; k++) {
        int i = base + k;
        if (i < N_NODES) {
            int d = deg4[i] + deg4[N_NODES + i] + deg4[2 * N_NODES + i]
                  + deg4[3 * N_NODES + i];
            deg[i] = d;
            t += d;
        }
    }
    s[tid] = t;
    __syncthreads();
    for (int off = 128; off > 0; off >>= 1) {
        if (tid < off) s[tid] += s[tid + off];
        __syncthreads();
    }
    if (tid == 0) blksum[b] = s[0];
}

__global__ __launch_bounds__(256) void k_scan3(
    const int* __restrict__ deg, const int* __restrict__ blksum,
    int* __restrict__ offs, int* __restrict__ cursor)
{
    __shared__ int s[256];
    __shared__ int sbase;
    int b = blockIdx.x, tid = threadIdx.x;
    if (tid < 64) {
        int v = (tid < b) ? blksum[tid] : 0;
        #pragma unroll
        for (int d = 32; d >= 1; d >>= 1) v += __shfl_xor(v, d);
        if (tid == 0) sbase = v;
    }
    int base = b * SCAN_CHUNK + tid * 4;
    int d4[4]; int t = 0;
    #pragma unroll
    for (int k = 0; k < 4; k++) {
        int i = base + k;
        d4[k] = (i < N_NODES) ? deg[i] : 0;
        t += d4[k];
    }
    s[tid] = t;
    __syncthreads();
    for (int off = 1; off < 256; off <<= 1) {
        int v = (tid >= off) ? s[tid - off] : 0;
        __syncthreads();
        s[tid] += v;
        __syncthreads();
    }
    int excl = sbase + s[tid] - t;
    #pragma unroll
    for (int k = 0; k < 4; k++) {
        int i = base + k;
        if (i < N_NODES) { offs[i] = excl; cursor[i] = excl; }
        excl += d4[k];
    }
    if (b == NBLK_SCAN - 1 && tid == 255) offs[N_NODES] = excl;
}

__global__ __launch_bounds__(256) void k_scatter(
    const int* __restrict__ edge_index, const int* __restrict__ edge_type,
    const int* __restrict__ node_type, int* __restrict__ cursor,
    int* __restrict__ csrp)
{
    int e = blockIdx.x * 256 + threadIdx.x;
    if (e < N_EDGES) {
        int d  = edge_index[N_EDGES + e];
        int s  = edge_index[e];
        int et = edge_type[e];
        int ts = node_type[s];
        int pos = atomicAdd(&cursor[d], 1);
        csrp[pos] = s | (et << 16) | (ts << 19);
    }
}

// ---------------------------------------------------------------------------
// Layer-0 edge phase: p from precomputed LDS table (no exp in loop).
// Writes x1 bf16 (MFMA A operand).
// ---------------------------------------------------------------------------
__global__ __launch_bounds__(256) void k_layer0(
    const int* __restrict__ node_type, const int* __restrict__ offs,
    const int* __restrict__ csrp,
    const float* __restrict__ t_h0, const float* __restrict__ t_exp,
    const float* __restrict__ b0, u16* __restrict__ x1b)
{
    __shared__ float s_h0[NTT * HC];                 // 8 KB
    __shared__ float s_exp[NTT * NRR * NTT * NHEAD]; // 6 KB
    __shared__ float s_b0[CDIM];

    int tid = threadIdx.x;
    for (int i = tid; i < NTT * HC; i += 256) s_h0[i] = t_h0[i];
    for (int i = tid; i < NTT * NRR * NTT * NHEAD; i += 256) s_exp[i] = t_exp[i];
    if (tid < CDIM) s_b0[tid] = b0[tid];
    __syncthreads();

    int n = (blockIdx.x * 256 + tid) >> 6;
    int lane = tid & 63;
    int h = lane >> 4;
    int cq = (lane & 15) << 2;
    int hoff = h * CDIM + cq;

    int tnbase = node_type[n] * 192 + h;
    int e0 = offs[n], e1 = offs[n + 1];
    int efull = e0 + ((e1 - e0) & ~3);
    float ax = 0.f, ay = 0.f, az = 0.f, aw = 0.f, den = 0.f;
    for (int i = e0; i < efull; i += 4) {
        int rA = csrp[i],     rB = csrp[i + 1];
        int rC = csrp[i + 2], rD = csrp[i + 3];
        int tA = rA >> 19, tB = rB >> 19, tC = rC >> 19, tD = rD >> 19;
        int eA = (rA >> 16) & 7, eB = (rB >> 16) & 7;
        int eC = (rC >> 16) & 7, eD = (rD >> 16) & 7;
        float pA = s_exp[tnbase + (eA << 5) + (tA << 2)];
        float pB = s_exp[tnbase + (eB << 5) + (tB << 2)];
        float pC = s_exp[tnbase + (eC << 5) + (tC << 2)];
        float pD = s_exp[tnbase + (eD << 5) + (tD << 2)];
        den += pA + pB + pC + pD;
        const float4 vA = *(const float4*)(s_h0 + tA * HC + hoff);
        const float4 vB = *(const float4*)(s_h0 + tB * HC + hoff);
        const float4 vC = *(const float4*)(s_h0 + tC * HC + hoff);
        const float4 vD = *(const float4*)(s_h0 + tD * HC + hoff);
        ax += pA * vA.x + pB * vB.x + pC * vC.x + pD * vD.x;
        ay += pA * vA.y + pB * vB.y + pC * vC.y + pD * vD.y;
        az += pA * vA.z + pB * vB.z + pC * vC.z + pD * vD.z;
        aw += pA * vA.w + pB * vB.w + pC * vC.w + pD * vD.w;
    }
    for (int i = efull; i < e1; i++) {
        int r = csrp[i];
        int ts = r >> 19, et = (r >> 16) & 7;
        float p = s_exp[tnbase + (et << 5) + (ts << 2)];
        den += p;
        const float4 v = *(const float4*)(s_h0 + ts * HC + hoff);
        ax += p * v.x; ay += p * v.y; az += p * v.z; aw += p * v.w;
    }
    float inv = 0.25f / (den + 1e-16f);
    ax *= inv; ay *= inv; az *= inv; aw *= inv;
    ax += __shfl_xor(ax, 16); ax += __shfl_xor(ax, 32);
    ay += __shfl_xor(ay, 16); ay += __shfl_xor(ay, 32);
    az += __shfl_xor(az, 16); az += __shfl_xor(az, 32);
    aw += __shfl_xor(aw, 16); aw += __shfl_xor(aw, 32);
    if (lane < 16) {
        ushort4 o;
        o.x = f2u(eluf(ax + s_b0[cq + 0]));
        o.y = f2u(eluf(ay + s_b0[cq + 1]));
        o.z = f2u(eluf(az + s_b0[cq + 2]));
        o.w = f2u(eluf(aw + s_b0[cq + 3]));
        *(ushort4*)(x1b + (size_t)n * CDIM + cq) = o;
    }
}

// ---------------------------------------------------------------------------
// h1 = x1 @ W1 via MFMA (HW-verified layouts). h1 stored FP8 e4m3, x1024.
// ---------------------------------------------------------------------------
__global__ __launch_bounds__(256) void k_gemm1(
    const u16* __restrict__ x1b, const float* __restrict__ W1,
    const float* __restrict__ as1, const float* __restrict__ ad1,
    u8* __restrict__ h1f8, float* __restrict__ asrc1, float* __restrict__ adst1)
{
    __shared__ u8 ht[16 * HC];   // 4 KB (fp8)
    int tid = threadIdx.x;
    int lane = tid & 63, wv = tid >> 6;
    int quad = lane >> 4, c16 = lane & 15;

    bf8 bf[4][2];
    float sv[4], dv[4];
    #pragma unroll
    for (int t = 0; t < 4; t++) {
        int col = wv * 64 + t * 16 + c16;
        sv[t] = as1[col];
        dv[t] = ad1[col];
        #pragma unroll
        for (int kf = 0; kf < 2; kf++)
            #pragma unroll
            for (int j = 0; j < 8; j++)
                bf[t][kf][j] = (short)f2u(W1[(kf * 32 + quad * 8 + j) * HC + col]);
    }

    for (int it = 0; it < 5; it++) {
        int nt = it * 625 + blockIdx.x;
        const bf8 a0 = *(const bf8*)(x1b + (size_t)(nt * 16 + c16) * CDIM + quad * 8);
        const bf8 a1 = *(const bf8*)(x1b + (size_t)(nt * 16 + c16) * CDIM + 32 + quad * 8);
        f4 acc[4];
        #pragma unroll
        for (int t = 0; t < 4; t++) {
            acc[t] = (f4){0.f, 0.f, 0.f, 0.f};
            acc[t] = __builtin_amdgcn_mfma_f32_16x16x32_bf16(a0, bf[t][0], acc[t], 0, 0, 0);
            acc[t] = __builtin_amdgcn_mfma_f32_16x16x32_bf16(a1, bf[t][1], acc[t], 0, 0, 0);
        }
        float rs[4] = {0.f, 0.f, 0.f, 0.f}, rd[4] = {0.f, 0.f, 0.f, 0.f};
        #pragma unroll
        for (int t = 0; t < 4; t++)
            #pragma unroll
            for (int reg = 0; reg < 4; reg++) {
                float v = acc[t][reg];
                rs[reg] += v * sv[t];
                rd[reg] += v * dv[t];
                ht[(quad * 4 + reg) * HC + wv * 64 + t * 16 + c16] = f2fp8(v * H1SCALE);
            }
        #pragma unroll
        for (int reg = 0; reg < 4; reg++)
            #pragma unroll
            for (int d = 1; d < 16; d <<= 1) {
                rs[reg] += __shfl_xor(rs[reg], d);
                rd[reg] += __shfl_xor(rd[reg], d);
            }
        if (c16 == 0) {
            #pragma unroll
            for (int reg = 0; reg < 4; reg++) {
                int n = nt * 16 + quad * 4 + reg;
                asrc1[n * NHEAD + wv] = rs[reg];
                adst1[n * NHEAD + wv] = rd[reg];
            }
        }
        __syncthreads();
        const uint4* src = (const uint4*)ht;            // 256 x 16B = 4 KB
        uint4* dst = (uint4*)(h1f8 + (size_t)nt * 16 * HC);
        dst[tid] = src[tid];
        __syncthreads();
    }
}

// ---------------------------------------------------------------------------
// Layer 1 aggregation + ELU -> x2. h1 gathers are FP8 (half the fetch bytes);
// decode 4 channels with 2 cvt_pk instructions; 1/H1SCALE folded into inv.
// ---------------------------------------------------------------------------
__global__ __launch_bounds__(256) void k_agg1(
    const int* __restrict__ offs, const int* __restrict__ csrp,
    const u8* __restrict__ h1f8, const float* __restrict__ asrc1,
    const float* __restrict__ adst1, const float* __restrict__ t_ae1,
    const float* __restrict__ b1, float* __restrict__ x2)
{
    __shared__ float s_ae[NRR * NHEAD];
    if (threadIdx.x < NRR * NHEAD) s_ae[threadIdx.x] = t_ae1[threadIdx.x];
    __syncthreads();

    int n = (blockIdx.x * 256 + threadIdx.x) >> 6;
    int lane = threadIdx.x & 63;
    int h = lane >> 4;
    int cq = (lane & 15) << 2;
    float adst = adst1[n * NHEAD + h];
    int e0 = offs[n], e1 = offs[n + 1];
    int efull = e0 + ((e1 - e0) & ~7);

    float ax = 0.f, ay = 0.f, az = 0.f, aw = 0.f, den = 0.f;
    for (int i = e0; i < efull; i += 8) {
        int rec[8], s[8], et[8];
        #pragma unroll
        for (int k = 0; k < 8; k++) rec[k] = csrp[i + k];
        #pragma unroll
        for (int k = 0; k < 8; k++) { s[k] = rec[k] & 0xFFFF; et[k] = (rec[k] >> 16) & 7; }
        float asv[8];
        unsigned int hw[8];
        #pragma unroll
        for (int k = 0; k < 8; k++) asv[k] = asrc1[s[k] * NHEAD + h];
        #pragma unroll
        for (int k = 0; k < 8; k++)
            hw[k] = *(const unsigned int*)(h1f8 + (size_t)s[k] * HC + h * CDIM + cq);
        #pragma unroll
        for (int k = 0; k < 8; k++) {
            float p = __expf(lrelu(asv[k] + adst + s_ae[et[k] * NHEAD + h]));
            den += p;
            v2f lo = __builtin_amdgcn_cvt_pk_f32_fp8(hw[k], false);
            v2f hi = __builtin_amdgcn_cvt_pk_f32_fp8(hw[k], true);
            ax += p * lo.x; ay += p * lo.y;
            az += p * hi.x; aw += p * hi.y;
        }
    }
    for (int i = efull; i < e1; i++) {
        int rec = csrp[i];
        int s = rec & 0xFFFF, et = (rec >> 16) & 7;
        float p = __expf(lrelu(asrc1[s * NHEAD + h] + adst + s_ae[et * NHEAD + h]));
        den += p;
        unsigned int w = *(const unsigned int*)(h1f8 + (size_t)s * HC + h * CDIM + cq);
        v2f lo = __builtin_amdgcn_cvt_pk_f32_fp8(w, false);
        v2f hi = __builtin_amdgcn_cvt_pk_f32_fp8(w, true);
        ax += p * lo.x; ay += p * lo.y;
        az += p * hi.x; aw += p * hi.y;
    }
    float inv = (0.25f / H1SCALE) / (den + 1e-16f);
    ax *= inv; ay *= inv; az *= inv; aw *= inv;
    ax += __shfl_xor(ax, 16); ax += __shfl_xor(ax, 32);
    ay += __shfl_xor(ay, 16); ay += __shfl_xor(ay, 32);
    az += __shfl_xor(az, 16); az += __shfl_xor(az, 32);
    aw += __shfl_xor(aw, 16); aw += __shfl_xor(aw, 32);
    if (lane < 16) {
        float4 o;
        o.x = eluf(ax + b1[cq + 0]);
        o.y = eluf(ay + b1[cq + 1]);
        o.z = eluf(az + b1[cq + 2]);
        o.w = eluf(aw + b1[cq + 3]);
        *(float4*)(x2 + (size_t)n * CDIM + cq) = o;
    }
}

// ---------------------------------------------------------------------------
// FUSED mean-pool + classifier (+ diag in block 0, fires only on fault)
// ---------------------------------------------------------------------------
__global__ __launch_bounds__(256) void k_poolcls(
    const float* __restrict__ x2, const int* __restrict__ goffs,
    const float* __restrict__ cw1, const float* __restrict__ cb1,
    const float* __restrict__ cw2, const float* __restrict__ cb2,
    float* __restrict__ out, int wsMB,
    const int* __restrict__ offs, const int* __restrict__ csrp,
    const float* __restrict__ W1)
{
    __shared__ float part[4][CDIM];
    __shared__ float gsh[CDIM];
    int g = blockIdx.x;
    int ch = threadIdx.x & 63, rg = threadIdx.x >> 6;
    int gs = goffs[g], ge = goffs[g + 1];
    float acc = 0.f;
    for (int r = gs + rg; r < ge; r += 4)
        acc += x2[(size_t)r * CDIM + ch];
    part[rg][ch] = acc;
    __syncthreads();
    if (threadIdx.x < CDIM) {
        float s = part[0][ch] + part[1][ch] + part[2][ch] + part[3][ch];
        int c = ge - gs;
        gsh[ch] = s / (float)(c > 1 ? c : 1);
    }
    __syncthreads();
    if (threadIdx.x < 64) {
        int j = threadIdx.x;
        float a = cb1[j];
        #pragma unroll
        for (int k = 0; k < CDIM; k++) a += gsh[k] * cw1[k * CDIM + j];
        float hid = a > 0.f ? a : 0.f;
        float o0 = hid * cw2[j * 2 + 0];
        float o1 = hid * cw2[j * 2 + 1];
        #pragma unroll
        for (int d = 32; d >= 1; d >>= 1) {
            o0 += __shfl_xor(o0, d);
            o1 += __shfl_xor(o1, d);
        }
        if (j == 0) {
            out[g * 2 + 0] = o0 + cb2[0];
            out[g * 2 + 1] = o1 + cb2[1];
        }
    }
    if (g == 0) {
        __shared__ int simpl, soob, sA;
        if (threadIdx.x == 0) { simpl = 0; soob = 0; sA = 0; }
        __syncthreads();
        if (threadIdx.x == 0 && offs[N_NODES] != N_EDGES) atomicOr(&sA, 4);
        float v = W1[threadIdx.x];
        if (!(fabsf(v) < 100.f)) atomicAdd(&simpl, 1);
        int r = csrp[threadIdx.x];
        if ((r & 0xFFFF) >= N_NODES || (r >> 22) != 0 || r < 0) atomicAdd(&soob, 1);
        __syncthreads();
        if (threadIdx.x == 0) {
            int A = sA;
            if (simpl > 10) A |= 8;
            int B = soob > 1023 ? 1023 : soob;
            if (A | B) out[0] = (float)((A << 20) | (wsMB << 10) | B);
        }
    }
}

__global__ void k_fault(int code, float* __restrict__ out)
{
    if (threadIdx.x == 0 && blockIdx.x == 0) out[0] = (float)code;
}

// ---------------------------------------------------------------------------
extern "C" void kernel_launch(void* const* d_in, const int* in_sizes, int n_in,
                              void* d_out, int out_size, void* d_ws, size_t ws_size,
                              hipStream_t stream) {
    static const int rsize[22] = {50000, 800000, 1600000, 50000, 512, 96,
                                  16384, 4096, 256, 256, 256, 64,
                                  16384, 4096, 256, 256, 256, 64,
                                  4096, 64, 128, 2};
    static const int cand_pos[3][22] = {
        {21,19,18,12,20,17,0,2,8,4,6,10,1,3,9,5,7,11,15,13,16,14},   // ASCII sorted (R7)
        {0,1,2,3,4,5,6,7,8,9,10,11,12,13,14,15,16,17,18,19,20,21},   // dict order
        {17,15,14,8,16,13,18,20,4,0,2,6,19,21,5,1,3,7,11,9,12,10},   // case-insens
    };
    int mc = -1;
    if (n_in == 22) {
        for (int c = 0; c < 3 && mc < 0; c++) {
            bool ok = true;
            for (int r = 0; r < 22; r++)
                if (in_sizes[cand_pos[c][r]] != rsize[r]) { ok = false; break; }
            if (ok) mc = c;
        }
    }

    char* ws = (char*)d_ws;
    size_t off = 0;
    auto alloc = [&](size_t b) { size_t r = off; off += (b + 255) & ~(size_t)255; return r; };
    int*   deg4   = (int*)(ws + alloc((size_t)4 * N_NODES * 4));   // zeroed
    size_t zero_bytes = off;
    int*   deg    = (int*)(ws + alloc(N_NODES * 4));
    int*   blksum = (int*)(ws + alloc(NBLK_SCAN * 4));
    int*   offs   = (int*)(ws + alloc((N_NODES + 1) * 4));
    int*   cursor = (int*)(ws + alloc(N_NODES * 4));
    int*   csrp   = (int*)(ws + alloc(N_EDGES * 4));
    int*   goffs  = (int*)(ws + alloc((N_GRAPH + 1) * 4));
    float* t_h0   = (float*)(ws + alloc(NTT * HC * 4));
    float* t_as0  = (float*)(ws + alloc(NTT * NHEAD * 4));
    float* t_ad0  = (float*)(ws + alloc(NTT * NHEAD * 4));
    float* t_ae0  = (float*)(ws + alloc(NRR * NHEAD * 4));
    float* t_ae1  = (float*)(ws + alloc(NRR * NHEAD * 4));
    float* t_exp  = (float*)(ws + alloc(NTT * NRR * NTT * NHEAD * 4));
    u16*   x1b    = (u16*)(ws + alloc((size_t)N_NODES * CDIM * 2));
    float* asrc1  = (float*)(ws + alloc((size_t)N_NODES * NHEAD * 4));
    float* adst1  = (float*)(ws + alloc((size_t)N_NODES * NHEAD * 4));
    u8*    h1f8   = (u8*)(ws + alloc((size_t)N_NODES * HC));
    float* x2     = (float*)(ws + alloc((size_t)N_NODES * CDIM * 4));

    int wsMB = (int)(ws_size >> 20); if (wsMB > 1023) wsMB = 1023;
    int hostA = 0, hostB = 0;
    if (mc < 0) { hostA |= 1; hostB = (n_in != 22) ? (n_in < 1023 ? n_in : 1023) : 0; }
    if (mc >= 0 && off > ws_size) hostA |= 2;

    if (hostA == 0) {
        const int* P = cand_pos[mc];
        const int*   node_type  = (const int*)d_in[P[0]];
        const int*   edge_type  = (const int*)d_in[P[1]];
        const int*   edge_index = (const int*)d_in[P[2]];
        const int*   batch      = (const int*)d_in[P[3]];
        const float* node_emb   = (const float*)d_in[P[4]];
        const float* edge_emb   = (const float*)d_in[P[5]];
        const float* W0  = (const float*)d_in[P[6]];
        const float* We0 = (const float*)d_in[P[7]];
        const float* as0 = (const float*)d_in[P[8]];
        const float* ad0 = (const float*)d_in[P[9]];
        const float* ae0 = (const float*)d_in[P[10]];
        const float* b0  = (const float*)d_in[P[11]];
        const float* W1  = (const float*)d_in[P[12]];
        const float* We1 = (const float*)d_in[P[13]];
        const float* as1 = (const float*)d_in[P[14]];
        const float* ad1 = (const float*)d_in[P[15]];
        const float* ae1 = (const float*)d_in[P[16]];
        const float* b1  = (const float*)d_in[P[17]];
        const float* cw1 = (const float*)d_in[P[18]];
        const float* cb1 = (const float*)d_in[P[19]];
        const float* cw2 = (const float*)d_in[P[20]];
        const float* cb2 = (const float*)d_in[P[21]];

        int zero_elems = (int)(zero_bytes / 4);
        k_zero<<<(zero_elems + 255) / 256, 256, 0, stream>>>((float*)ws, zero_elems);
        k_tables<<<NTT + NRR, 256, 0, stream>>>(node_emb, edge_emb, W0, We0, as0,
                                                ad0, ae0, We1, ae1,
                                                t_h0, t_as0, t_ad0, t_ae0, t_ae1);
        k_exptab<<<1, 256, 0, stream>>>(t_as0, t_ad0, t_ae0, t_exp);
        k_count<<<(N_EDGES + 255) / 256, 256, 0, stream>>>(edge_index, deg4,
                                                           batch, goffs);
        k_scan1<<<NBLK_SCAN, 256, 0, stream>>>(deg4, deg, blksum);
        k_scan3<<<NBLK_SCAN, 256, 0, stream>>>(deg, blksum, offs, cursor);
        k_scatter<<<(N_EDGES + 255) / 256, 256, 0, stream>>>(edge_index, edge_type,
                                                             node_type, cursor, csrp);
        k_layer0<<<(N_NODES * 64) / 256, 256, 0, stream>>>(
            node_type, offs, csrp, t_h0, t_exp, b0, x1b);
        k_gemm1<<<625, 256, 0, stream>>>(
            x1b, W1, as1, ad1, h1f8, asrc1, adst1);
        k_agg1<<<(N_NODES * 64) / 256, 256, 0, stream>>>(
            offs, csrp, h1f8, asrc1, adst1, t_ae1, b1, x2);
        k_poolcls<<<N_GRAPH, 256, 0, stream>>>(
            x2, goffs, cw1, cb1, cw2, cb2, (float*)d_out, wsMB, offs, csrp, W1);
    } else {
        int code = (hostA << 20) | (wsMB << 10) | (hostB > 1023 ? 1023 : hostB);
        k_fault<<<1, 64, 0, stream>>>(code, (float*)d_out);
    }
}